// Round 5
// baseline (380.395 us; speedup 1.0000x reference)
//
#include <hip/hip_runtime.h>

#define B_      8
#define N_      2048
#define DIM_    1024
#define HEADS_  8
#define CBD_    64
#define CBS_    1024
#define CBIN_   512              // HEADS_*CBD_
#define M_      (B_*N_)          // 16384 rows
#define M2_     (M_*HEADS_)      // 131072 row-heads

#define XSTR   40                // LDS stride (elements) for gemm_in 32-k bf16 planes
#define MARGIN 0.02f             // >> deterministic bf16x3 score error bound (~2.4e-3)

typedef unsigned short ushort_t;
typedef __attribute__((ext_vector_type(8))) short short8;
typedef __attribute__((ext_vector_type(4))) float f32x4;

__device__ inline ushort_t f2bf(float f) {
    unsigned int u = __builtin_bit_cast(unsigned int, f);
    unsigned int r = u + 0x7FFFu + ((u >> 16) & 1u);
    return (ushort_t)(r >> 16);
}
__device__ inline float bf2f(ushort_t h) {
    unsigned int u = ((unsigned int)h) << 16;
    return __builtin_bit_cast(float, u);
}
__device__ inline f32x4 mfma_bf16(short8 a, short8 b, f32x4 c) {
    return __builtin_amdgcn_mfma_f32_16x16x32_bf16(a, b, c, 0, 0, 0);
}
__device__ inline void store4u(ushort_t* p, ushort_t a, ushort_t b, ushort_t c, ushort_t d) {
    uint2 u;
    u.x = (unsigned int)a | ((unsigned int)b << 16);
    u.y = (unsigned int)c | ((unsigned int)d << 16);
    *(uint2*)p = u;
}
__device__ inline void split3(float f, ushort_t& s1, ushort_t& s2, ushort_t& s3) {
    s1 = f2bf(f);
    float r = f - bf2f(s1);
    s2 = f2bf(r);
    float r2 = r - bf2f(s2);
    s3 = f2bf(r2);
}

// ---------------- prep: esq[c] = sum_d embed[c][d]^2 (fp32) ----------------
__global__ __launch_bounds__(256) void esq_kernel(const float* __restrict__ embed,
                                                  float* __restrict__ esq) {
    int c = blockIdx.x * 256 + threadIdx.x;
    if (c < CBS_) {
        const float* e = embed + (size_t)c * CBD_;
        float s = 0.f;
#pragma unroll
        for (int d = 0; d < CBD_; ++d) s += e[d] * e[d];
        esq[c] = s;
    }
}

// ---------------- prep: split embed into bf16 hi/lo ----------------
__global__ __launch_bounds__(256) void split_embed(const float* __restrict__ embed,
                                                   ushort_t* __restrict__ hi,
                                                   ushort_t* __restrict__ lo) {
    int i = blockIdx.x * 256 + threadIdx.x;   // 65536 total
    float f = embed[i];
    ushort_t h = f2bf(f);
    hi[i] = h;
    lo[i] = f2bf(f - bf2f(h));
}

// ---------------- prep: WbfT[n][k] = bf16(W_out[k][n]) ----------------
__global__ __launch_bounds__(256) void transposeW(const float* __restrict__ W,
                                                  ushort_t* __restrict__ WT) {
    __shared__ ushort_t t[64][65];
    const int tid = threadIdx.x;
    const int n0 = blockIdx.x * 64, k0 = blockIdx.y * 64;
#pragma unroll
    for (int s = 0; s < 16; ++s) {
        int i = s * 256 + tid;
        int r = i >> 6, c = i & 63;
        t[r][c] = f2bf(W[(size_t)(k0 + r) * DIM_ + n0 + c]);
    }
    __syncthreads();
#pragma unroll
    for (int s = 0; s < 16; ++s) {
        int i = s * 256 + tid;
        int r = i >> 6, c = i & 63;
        WT[(size_t)(n0 + r) * CBIN_ + k0 + c] = t[c][r];
    }
}

// ---------------- prep: 3-way split + transpose of W_in: WpT[n][k] ----------------
__global__ __launch_bounds__(256) void split_WinT(const float* __restrict__ W,
                                                  ushort_t* __restrict__ W1T,
                                                  ushort_t* __restrict__ W2T,
                                                  ushort_t* __restrict__ W3T) {
    __shared__ ushort_t t1[64][65];
    __shared__ ushort_t t2[64][65];
    __shared__ ushort_t t3[64][65];
    const int tid = threadIdx.x;
    const int n0 = blockIdx.x * 64, k0 = blockIdx.y * 64;
#pragma unroll
    for (int s = 0; s < 16; ++s) {
        int i = s * 256 + tid;
        int r = i >> 6, c = i & 63;
        float f = W[(size_t)(k0 + r) * CBIN_ + n0 + c];
        split3(f, t1[r][c], t2[r][c], t3[r][c]);
    }
    __syncthreads();
#pragma unroll
    for (int s = 0; s < 16; ++s) {
        int i = s * 256 + tid;
        int r = i >> 6, c = i & 63;
        size_t o = (size_t)(n0 + r) * DIM_ + k0 + c;
        W1T[o] = t1[c][r];
        W2T[o] = t2[c][r];
        W3T[o] = t3[c][r];
    }
}

// ---------------- GEMM1 via bf16x6 MFMA: h[M,512] = x @ W_in + b_in (R3-proven) --------
__global__ __launch_bounds__(256) void gemm_in_x6(const float* __restrict__ x,
                                                  const ushort_t* __restrict__ W1T,
                                                  const ushort_t* __restrict__ W2T,
                                                  const ushort_t* __restrict__ W3T,
                                                  const float* __restrict__ bias,
                                                  float* __restrict__ C) {
    __shared__ ushort_t A1[128 * XSTR];
    __shared__ ushort_t A2[128 * XSTR];
    __shared__ ushort_t A3[128 * XSTR];
    __shared__ ushort_t B1[128 * XSTR];
    __shared__ ushort_t B2[128 * XSTR];
    __shared__ ushort_t B3[128 * XSTR];

    const int tid  = threadIdx.x;
    const int lane = tid & 63;
    const int w    = tid >> 6;
    const int quad = lane >> 4;
    const int col  = lane & 15;
    const int m0   = blockIdx.y * 128;
    const int n0   = blockIdx.x * 128;
    const int wm   = (w & 1) * 64;
    const int wn   = (w >> 1) * 64;

    f32x4 acc[4][4];
#pragma unroll
    for (int rt = 0; rt < 4; ++rt)
#pragma unroll
        for (int ct = 0; ct < 4; ++ct) acc[rt][ct] = (f32x4){0.f, 0.f, 0.f, 0.f};

    for (int k0 = 0; k0 < DIM_; k0 += 32) {
        __syncthreads();
#pragma unroll
        for (int s = 0; s < 4; ++s) {
            int f = s * 256 + tid;
            int row = f >> 3, qq = f & 7;
            float4 v = *(const float4*)(x + (size_t)(m0 + row) * DIM_ + k0 + qq * 4);
            float vv[4] = {v.x, v.y, v.z, v.w};
            ushort_t p1[4], p2[4], p3[4];
#pragma unroll
            for (int j = 0; j < 4; ++j) split3(vv[j], p1[j], p2[j], p3[j]);
            int base = row * XSTR + qq * 4;
            store4u(&A1[base], p1[0], p1[1], p1[2], p1[3]);
            store4u(&A2[base], p2[0], p2[1], p2[2], p2[3]);
            store4u(&A3[base], p3[0], p3[1], p3[2], p3[3]);
        }
#pragma unroll
        for (int s = 0; s < 2; ++s) {
            int f = s * 256 + tid;
            int row = f >> 2, g = f & 3;
            size_t go = (size_t)(n0 + row) * DIM_ + k0 + g * 8;
            int lo = row * XSTR + g * 8;
            *(uint4*)&B1[lo] = *(const uint4*)(W1T + go);
            *(uint4*)&B2[lo] = *(const uint4*)(W2T + go);
            *(uint4*)&B3[lo] = *(const uint4*)(W3T + go);
        }
        __syncthreads();

        short8 a1[4], a2[4], a3[4], b1[4], b2[4], b3[4];
#pragma unroll
        for (int rt = 0; rt < 4; ++rt) {
            int o = (wm + rt * 16 + col) * XSTR + quad * 8;
            a1[rt] = *(const short8*)&A1[o];
            a2[rt] = *(const short8*)&A2[o];
            a3[rt] = *(const short8*)&A3[o];
        }
#pragma unroll
        for (int ct = 0; ct < 4; ++ct) {
            int o = (wn + ct * 16 + col) * XSTR + quad * 8;
            b1[ct] = *(const short8*)&B1[o];
            b2[ct] = *(const short8*)&B2[o];
            b3[ct] = *(const short8*)&B3[o];
        }
#define COMBO(AP, BP)                                                   \
        _Pragma("unroll")                                               \
        for (int ct = 0; ct < 4; ++ct)                                  \
            _Pragma("unroll")                                           \
            for (int rt = 0; rt < 4; ++rt)                              \
                acc[rt][ct] = mfma_bf16(AP[rt], BP[ct], acc[rt][ct]);
        COMBO(a1, b1); COMBO(a1, b2); COMBO(a2, b1);
        COMBO(a2, b2); COMBO(a1, b3); COMBO(a3, b1);
#undef COMBO
    }

#pragma unroll
    for (int ct = 0; ct < 4; ++ct) {
        int gc = n0 + wn + ct * 16 + col;
        float bb = bias[gc];
#pragma unroll
        for (int rt = 0; rt < 4; ++rt) {
#pragma unroll
            for (int reg = 0; reg < 4; ++reg) {
                int gr = m0 + wm + rt * 16 + quad * 4 + reg;
                C[(size_t)gr * CBIN_ + gc] = acc[rt][ct][reg] + bb;
            }
        }
    }
}

// ---------------- argmax4: argmax2 core, A-frags direct from global (no HX LDS) --------
// 128 row-heads/block, 4 waves x 32 rows; codebook streamed in 64-code chunks through
// padded LDS (proven R2/R3 layout); fp32 top-2 bookkeeping + MARGIN flag + exact fallback.
__global__ __launch_bounds__(256) void argmax4(const float* __restrict__ h,
                                               const ushort_t* __restrict__ embhi,
                                               const ushort_t* __restrict__ emblo,
                                               const float* __restrict__ esq,
                                               const float* __restrict__ embed,
                                               float* __restrict__ outIdxF,
                                               int* __restrict__ outIdxI) {
    __shared__ ushort_t EBHI[64 * 72];
    __shared__ ushort_t EBLO[64 * 72];
    __shared__ float    ESQ[CBS_];
    __shared__ int      BIDX[128];
    __shared__ int      FLAG[128];
    __shared__ int      NFLAG;

    const int tid  = threadIdx.x;
    const int lane = tid & 63;
    const int w    = tid >> 6;
    const int quad = lane >> 4;
    const int col  = lane & 15;
    const int r0   = blockIdx.x * 128;

    if (tid == 0) NFLAG = 0;

    *(float4*)&ESQ[tid * 4] = *(const float4*)(esq + tid * 4);

    // A-fragments straight from global h, hi/lo split in registers
    // (address-identical to argmax2's HXHI[m*72 + ks*32 + quad*8] elements)
    short8 AH[2][2], AL[2][2];
#pragma unroll
    for (int rt = 0; rt < 2; ++rt)
#pragma unroll
        for (int ks = 0; ks < 2; ++ks) {
            const float* p = h + (size_t)(r0 + w * 32 + rt * 16 + col) * 64 + ks * 32 + quad * 8;
            float4 v0 = *(const float4*)p;
            float4 v1_ = *(const float4*)(p + 4);
            float vv[8] = {v0.x, v0.y, v0.z, v0.w, v1_.x, v1_.y, v1_.z, v1_.w};
            short8 hh, ll;
#pragma unroll
            for (int j = 0; j < 8; ++j) {
                ushort_t hi = f2bf(vv[j]);
                ushort_t lo = f2bf(vv[j] - bf2f(hi));
                hh[j] = (short)hi;
                ll[j] = (short)lo;
            }
            AH[rt][ks] = hh;
            AL[rt][ks] = ll;
        }

    float v1[8], v2[8];
    int   i1[8];
#pragma unroll
    for (int s = 0; s < 8; ++s) { v1[s] = -3.4e38f; v2[s] = -3.4e38f; i1[s] = 0; }

    for (int ch = 0; ch < 16; ++ch) {
        __syncthreads();   // first iter: also covers ESQ staging
#pragma unroll
        for (int s = 0; s < 2; ++s) {
            int f = s * 256 + tid;
            int row = f >> 3, g = f & 7;
            *(uint4*)&EBHI[row * 72 + g * 8] =
                *(const uint4*)(embhi + (size_t)(ch * 64 + row) * 64 + g * 8);
            *(uint4*)&EBLO[row * 72 + g * 8] =
                *(const uint4*)(emblo + (size_t)(ch * 64 + row) * 64 + g * 8);
        }
        __syncthreads();
#pragma unroll
        for (int ct = 0; ct < 4; ++ct) {
            int nb = (ct * 16 + col) * 72 + quad * 8;
            short8 BH0 = *(const short8*)&EBHI[nb];
            short8 BH1 = *(const short8*)&EBHI[nb + 32];
            short8 BL0 = *(const short8*)&EBLO[nb];
            short8 BL1 = *(const short8*)&EBLO[nb + 32];
            int code = ch * 64 + ct * 16 + col;
            float eq = ESQ[code];
#pragma unroll
            for (int rt = 0; rt < 2; ++rt) {
                f32x4 acc = {0.f, 0.f, 0.f, 0.f};
                acc = mfma_bf16(AH[rt][0], BH0, acc);
                acc = mfma_bf16(AH[rt][1], BH1, acc);
                acc = mfma_bf16(AH[rt][0], BL0, acc);
                acc = mfma_bf16(AH[rt][1], BL1, acc);
                acc = mfma_bf16(AL[rt][0], BH0, acc);
                acc = mfma_bf16(AL[rt][1], BH1, acc);
#pragma unroll
                for (int reg = 0; reg < 4; ++reg) {
                    int st = rt * 4 + reg;
                    float sc = fmaf(2.f, acc[reg], -eq);
                    float losr = fminf(sc, v1[st]);
                    v2[st] = fmaxf(v2[st], losr);
                    bool gt = sc > v1[st];
                    v1[st] = fmaxf(v1[st], sc);
                    i1[st] = gt ? code : i1[st];
                }
            }
        }
    }

    // cross-lane merge over the 16 col-lanes (low 4 bits of lane)
#pragma unroll
    for (int st = 0; st < 8; ++st) {
#pragma unroll
        for (int m = 1; m <= 8; m <<= 1) {
            float ov1 = __shfl_xor(v1[st], m);
            int   oi1 = __shfl_xor(i1[st], m);
            float ov2 = __shfl_xor(v2[st], m);
            float losr = fminf(v1[st], ov1);
            v2[st] = fmaxf(fmaxf(v2[st], ov2), losr);
            bool take = (ov1 > v1[st]) || (ov1 == v1[st] && oi1 < i1[st]);
            v1[st] = take ? ov1 : v1[st];
            i1[st] = take ? oi1 : i1[st];
        }
        if (col == 0) {
            int rt = st >> 2, reg = st & 3;
            int row_l = w * 32 + rt * 16 + quad * 4 + reg;
            BIDX[row_l] = i1[st];
            if (v1[st] - v2[st] < MARGIN) {
                int p = atomicAdd(&NFLAG, 1);
                FLAG[p] = row_l;
            }
        }
    }
    __syncthreads();

    // exact fp32 fallback for ambiguous rows (identical numerics to R1-R3)
    int nf = NFLAG;
    for (int i = w; i < nf; i += 4) {
        int row_l = FLAG[i];
        const float* hr = h + (size_t)(r0 + row_l) * 64;
        float accf[16];
#pragma unroll
        for (int j = 0; j < 16; ++j) accf[j] = 0.f;
        for (int d4 = 0; d4 < 16; ++d4) {
            float4 hv = *(const float4*)(hr + d4 * 4);
#pragma unroll
            for (int j = 0; j < 16; ++j) {
                int c = lane + 64 * j;
                float4 ev = *(const float4*)(embed + (size_t)c * 64 + d4 * 4);
                accf[j] += hv.x * ev.x + hv.y * ev.y + hv.z * ev.z + hv.w * ev.w;
            }
        }
        float best = -3.4e38f; int bi = 0;
#pragma unroll
        for (int j = 0; j < 16; ++j) {
            int c = lane + 64 * j;
            float sc = 2.f * accf[j] - ESQ[c];
            if (sc > best) { best = sc; bi = c; }
        }
#pragma unroll
        for (int m = 1; m <= 32; m <<= 1) {
            float ob = __shfl_xor(best, m);
            int  obi = __shfl_xor(bi, m);
            if (ob > best || (ob == best && obi < bi)) { best = ob; bi = obi; }
        }
        if (lane == 0) BIDX[row_l] = bi;
    }
    __syncthreads();

    if (tid < 128) {
        int b = BIDX[tid];
        outIdxF[r0 + tid] = (float)b;
        outIdxI[r0 + tid] = b;
    }
}

// ---------------- GEMM3 (bf16 MFMA): out = gather(embhi, idx) @ W_out + b_out ----------
__global__ __launch_bounds__(256) void gemm_out_bf16(const ushort_t* __restrict__ embhi,
                                                     const int* __restrict__ idx,
                                                     const ushort_t* __restrict__ WbfT,
                                                     const float* __restrict__ bias,
                                                     float* __restrict__ C) {
    __shared__ ushort_t Qs[128 * 72];
    __shared__ ushort_t Ws[128 * 72];
    __shared__ int idxs[128 * HEADS_];

    const int tid  = threadIdx.x;
    const int lane = tid & 63;
    const int w    = tid >> 6;
    const int quad = lane >> 4;
    const int col  = lane & 15;
    const int m0   = blockIdx.y * 128;
    const int n0   = blockIdx.x * 128;
    const int wm   = (w & 1) * 64;
    const int wn   = (w >> 1) * 64;

#pragma unroll
    for (int s = 0; s < 4; ++s) {
        int f = s * 256 + tid;
        idxs[f] = idx[(size_t)m0 * HEADS_ + f];
    }

    f32x4 acc[4][4];
#pragma unroll
    for (int rt = 0; rt < 4; ++rt)
#pragma unroll
        for (int ct = 0; ct < 4; ++ct) acc[rt][ct] = (f32x4){0.f, 0.f, 0.f, 0.f};

    for (int k0 = 0; k0 < CBIN_; k0 += 64) {
        __syncthreads();
        int head = k0 >> 6;
#pragma unroll
        for (int s = 0; s < 4; ++s) {
            int f = s * 256 + tid;
            int row = f >> 3, g = f & 7;
            int e = idxs[row * HEADS_ + head];
            *(uint4*)&Qs[row * 72 + g * 8] = *(const uint4*)(embhi + (size_t)e * 64 + g * 8);
            *(uint4*)&Ws[row * 72 + g * 8] =
                *(const uint4*)(WbfT + (size_t)(n0 + row) * CBIN_ + k0 + g * 8);
        }
        __syncthreads();
#pragma unroll
        for (int ks = 0; ks < 2; ++ks) {
            short8 a[4], b[4];
#pragma unroll
            for (int rt = 0; rt < 4; ++rt)
                a[rt] = *(const short8*)&Qs[(wm + rt * 16 + col) * 72 + ks * 32 + quad * 8];
#pragma unroll
            for (int ct = 0; ct < 4; ++ct)
                b[ct] = *(const short8*)&Ws[(wn + ct * 16 + col) * 72 + ks * 32 + quad * 8];
#pragma unroll
            for (int rt = 0; rt < 4; ++rt)
#pragma unroll
                for (int ct = 0; ct < 4; ++ct)
                    acc[rt][ct] = mfma_bf16(a[rt], b[ct], acc[rt][ct]);
        }
    }

#pragma unroll
    for (int ct = 0; ct < 4; ++ct) {
        int gc = n0 + wn + ct * 16 + col;
        float bb = bias[gc];
#pragma unroll
        for (int rt = 0; rt < 4; ++rt) {
#pragma unroll
            for (int reg = 0; reg < 4; ++reg) {
                int gr = m0 + wm + rt * 16 + quad * 4 + reg;
                C[(size_t)gr * DIM_ + gc] = acc[rt][ct][reg] + bb;
            }
        }
    }
}

extern "C" void kernel_launch(void* const* d_in, const int* in_sizes, int n_in,
                              void* d_out, int out_size, void* d_ws, size_t ws_size,
                              hipStream_t stream) {
    const float* x     = (const float*)d_in[0];
    const float* W_in  = (const float*)d_in[1];
    const float* b_in  = (const float*)d_in[2];
    const float* W_out = (const float*)d_in[3];
    const float* b_out = (const float*)d_in[4];
    const float* embed = (const float*)d_in[5];

    float* out     = (float*)d_out;
    float* outIdxF = out + (size_t)M_ * DIM_;

    // workspace layout (38.5 MB total)
    char* ws = (char*)d_ws;
    float*    h     = (float*)ws;                                   // 33,554,432 B
    int*      idxI  = (int*)(ws + 33554432);                        //    524,288 B
    float*    esq   = (float*)(ws + 34078720);                      //      4,096 B
    ushort_t* embhi = (ushort_t*)(ws + 34082816);                   //    131,072 B
    ushort_t* emblo = (ushort_t*)(ws + 34213888);                   //    131,072 B
    ushort_t* WbfT  = (ushort_t*)(ws + 34344960);                   //  1,048,576 B
    ushort_t* W1T   = (ushort_t*)(ws + 35393536);                   //  1,048,576 B
    ushort_t* W2T   = (ushort_t*)(ws + 36442112);                   //  1,048,576 B
    ushort_t* W3T   = (ushort_t*)(ws + 37490688);                   //  1,048,576 B

    esq_kernel<<<dim3(CBS_ / 256), dim3(256), 0, stream>>>(embed, esq);
    split_embed<<<dim3(CBS_ * CBD_ / 256), dim3(256), 0, stream>>>(embed, embhi, emblo);
    transposeW<<<dim3(DIM_ / 64, CBIN_ / 64), dim3(256), 0, stream>>>(W_out, WbfT);
    split_WinT<<<dim3(CBIN_ / 64, DIM_ / 64), dim3(256), 0, stream>>>(W_in, W1T, W2T, W3T);
    gemm_in_x6<<<dim3(CBIN_ / 128, M_ / 128), dim3(256), 0, stream>>>(x, W1T, W2T, W3T,
                                                                      b_in, h);
    argmax4<<<dim3(M2_ / 128), dim3(256), 0, stream>>>(h, embhi, emblo, esq, embed,
                                                       outIdxF, idxI);
    gemm_out_bf16<<<dim3(DIM_ / 128, M_ / 128), dim3(256), 0, stream>>>(embhi, idxI, WbfT,
                                                                        b_out, out);
}